// Round 2
// baseline (840.512 us; speedup 1.0000x reference)
//
#include <hip/hip_runtime.h>
#include <math.h>

#define N_NODES 20000
#define N_EDGES 640000
#define IN_CH 64
#define EDGE_DIM 16
#define HID 128
#define N_LAYERS 3
#define N_GRAPHS 128

static_assert(N_NODES % 16 == 0, "NPB tiling");

// ---------------- CSR build ----------------

__global__ void hist_kernel(const int* __restrict__ dst, int* __restrict__ deg, int n) {
    int i = blockIdx.x * blockDim.x + threadIdx.x;
    if (i < n) atomicAdd(&deg[dst[i]], 1);
}

// exclusive prefix sum over N_NODES degrees -> rowptr[N_NODES+1]
__global__ __launch_bounds__(1024) void scan_kernel(const int* __restrict__ deg,
                                                    int* __restrict__ rowptr) {
    __shared__ int buf[1024];
    const int t = threadIdx.x;
    constexpr int PER = 20;           // 1024*20 >= 20000
    const int base = t * PER;
    int loc[PER];
    int s = 0;
    #pragma unroll
    for (int i = 0; i < PER; i++) {
        int v = (base + i < N_NODES) ? deg[base + i] : 0;
        loc[i] = s; s += v;
    }
    buf[t] = s;
    __syncthreads();
    for (int off = 1; off < 1024; off <<= 1) {
        int x = (t >= off) ? buf[t - off] : 0;
        __syncthreads();
        buf[t] += x;
        __syncthreads();
    }
    const int excl = (t == 0) ? 0 : buf[t - 1];
    #pragma unroll
    for (int i = 0; i < PER; i++)
        if (base + i < N_NODES) rowptr[base + i] = excl + loc[i];
    if (t == 1023) rowptr[N_NODES] = buf[1023];
}

__global__ void scatter_kernel(const int* __restrict__ ei, const int* __restrict__ rowptr,
                               int* __restrict__ cursor, int* __restrict__ csr_eid,
                               int* __restrict__ csr_src, int n) {
    int e = blockIdx.x * blockDim.x + threadIdx.x;
    if (e < n) {
        int d = ei[N_EDGES + e];
        int pos = atomicAdd(&cursor[d], 1);
        int slot = rowptr[d] + pos;
        csr_eid[slot] = e;
        csr_src[slot] = ei[e];
    }
}

// ---------------- node GEMM: out[N,128] = in[N,KIN] @ W[KIN,128] + bias ----------------

template<int KIN>
__global__ __launch_bounds__(128) void gemm_nodes(const float* __restrict__ in,
                                                  const float* __restrict__ W,
                                                  const float* __restrict__ bias,
                                                  float* __restrict__ out) {
    constexpr int NPB = 16;
    __shared__ __align__(16) float a[NPB * KIN];
    const int t = threadIdx.x;
    const int node0 = blockIdx.x * NPB;
    const float* src = in + (size_t)node0 * KIN;
    #pragma unroll
    for (int i = t * 4; i < NPB * KIN; i += 512)
        *(float4*)(a + i) = *(const float4*)(src + i);
    __syncthreads();
    float acc[NPB];
    const float bv = bias[t];
    #pragma unroll
    for (int n = 0; n < NPB; n++) acc[n] = bv;
    for (int k = 0; k < KIN; k += 4) {
        const float w0 = W[(k + 0) * HID + t];
        const float w1 = W[(k + 1) * HID + t];
        const float w2 = W[(k + 2) * HID + t];
        const float w3 = W[(k + 3) * HID + t];
        #pragma unroll
        for (int n = 0; n < NPB; n++) {
            const float4 av = *(const float4*)(a + n * KIN + k);
            acc[n] += av.x * w0 + av.y * w1 + av.z * w2 + av.w * w3;
        }
    }
    float* o = out + (size_t)node0 * HID + t;
    #pragma unroll
    for (int n = 0; n < NPB; n++) o[n * HID] = acc[n];
}

// ---------------- combined W2u = msg_w2 @ upd_w_bottom ----------------

__global__ __launch_bounds__(128) void w2u_kernel(const float* __restrict__ w2,
                                                  const float* __restrict__ b2,
                                                  const float* __restrict__ wu_bot,
                                                  float* __restrict__ W2u,
                                                  float* __restrict__ b2u) {
    __shared__ float row[HID];
    const int t = threadIdx.x, d = blockIdx.x;
    const float* src = (d < HID) ? (w2 + d * HID) : b2;
    row[t] = src[t];
    __syncthreads();
    float acc = 0.f;
    for (int k = 0; k < HID; k++) acc += row[k] * wu_bot[k * HID + t];
    if (d < HID) W2u[d * HID + t] = acc;
    else b2u[t] = acc;
}

// ---------------- edge aggregate: r[n] = sum_{e: dst=n} relu(npart[src] + ea@W1e) ----------------

__global__ __launch_bounds__(128) void edge_aggr(const float* __restrict__ npart,
                                                 const float* __restrict__ W1e,
                                                 const float* __restrict__ edge_attr,
                                                 const int* __restrict__ rowptr,
                                                 const int* __restrict__ csr_eid,
                                                 const int* __restrict__ csr_src,
                                                 float* __restrict__ r) {
    const int t = threadIdx.x;
    const int node = blockIdx.x;
    float w[EDGE_DIM];
    #pragma unroll
    for (int k = 0; k < EDGE_DIM; k++) w[k] = W1e[k * HID + t];
    const int beg = rowptr[node], end = rowptr[node + 1];
    float acc = 0.f;
    for (int i = beg; i < end; i++) {
        const int e = csr_eid[i];
        const int s = csr_src[i];
        float z = npart[(size_t)s * HID + t];
        const float4* ea = (const float4*)(edge_attr + (size_t)e * EDGE_DIM);
        const float4 e0 = ea[0], e1 = ea[1], e2 = ea[2], e3 = ea[3];
        z += e0.x * w[0]  + e0.y * w[1]  + e0.z * w[2]  + e0.w * w[3];
        z += e1.x * w[4]  + e1.y * w[5]  + e1.z * w[6]  + e1.w * w[7];
        z += e2.x * w[8]  + e2.y * w[9]  + e2.z * w[10] + e2.w * w[11];
        z += e3.x * w[12] + e3.y * w[13] + e3.z * w[14] + e3.w * w[15];
        acc += fmaxf(z, 0.f);
    }
    r[(size_t)node * HID + t] = acc;
}

// ---------------- fused update + LayerNorm + relu + residual (in-place on h) ----------------

__global__ __launch_bounds__(128) void update_nodes(float* __restrict__ h,
                                                    const float* __restrict__ r,
                                                    const int* __restrict__ deg,
                                                    const float* __restrict__ Wt,
                                                    const float* __restrict__ W2u,
                                                    const float* __restrict__ ub,
                                                    const float* __restrict__ b2u,
                                                    const float* __restrict__ lng,
                                                    const float* __restrict__ lnb) {
    constexpr int NPB = 16;
    __shared__ __align__(16) float sh[NPB * HID];
    __shared__ __align__(16) float sr[NPB * HID];
    __shared__ float smu[NPB], srs[NPB];
    const int t = threadIdx.x;
    const int node0 = blockIdx.x * NPB;
    #pragma unroll
    for (int i = t * 4; i < NPB * HID; i += 512) {
        *(float4*)(sh + i) = *(const float4*)(h + (size_t)node0 * HID + i);
        *(float4*)(sr + i) = *(const float4*)(r + (size_t)node0 * HID + i);
    }
    __syncthreads();
    float acc[NPB];
    const float ubv = ub[t], b2uv = b2u[t];
    #pragma unroll
    for (int n = 0; n < NPB; n++) acc[n] = ubv + (float)deg[node0 + n] * b2uv;
    for (int k = 0; k < HID; k += 4) {
        const float wt0 = Wt[(k + 0) * HID + t], w20 = W2u[(k + 0) * HID + t];
        const float wt1 = Wt[(k + 1) * HID + t], w21 = W2u[(k + 1) * HID + t];
        const float wt2 = Wt[(k + 2) * HID + t], w22 = W2u[(k + 2) * HID + t];
        const float wt3 = Wt[(k + 3) * HID + t], w23 = W2u[(k + 3) * HID + t];
        #pragma unroll
        for (int n = 0; n < NPB; n++) {
            const float4 hv = *(const float4*)(sh + n * HID + k);
            const float4 rv = *(const float4*)(sr + n * HID + k);
            acc[n] += hv.x * wt0 + hv.y * wt1 + hv.z * wt2 + hv.w * wt3;
            acc[n] += rv.x * w20 + rv.y * w21 + rv.z * w22 + rv.w * w23;
        }
    }
    #pragma unroll
    for (int n = 0; n < NPB; n++) acc[n] = fmaxf(acc[n], 0.f);   // u = relu(...)
    __syncthreads();                 // done reading sr
    #pragma unroll
    for (int n = 0; n < NPB; n++) sr[n * HID + t] = acc[n];
    __syncthreads();
    // LayerNorm stats: 8 threads per node
    {
        const int n = t >> 3, lane = t & 7;
        float s = 0.f, ss = 0.f;
        #pragma unroll
        for (int i = 0; i < 16; i++) {
            float v = sr[n * HID + lane + i * 8];
            s += v; ss += v * v;
        }
        s += __shfl_xor(s, 1); ss += __shfl_xor(ss, 1);
        s += __shfl_xor(s, 2); ss += __shfl_xor(ss, 2);
        s += __shfl_xor(s, 4); ss += __shfl_xor(ss, 4);
        if (lane == 0) {
            float mu = s * (1.f / HID);
            float var = ss * (1.f / HID) - mu * mu;
            smu[n] = mu;
            srs[n] = rsqrtf(var + 1e-5f);
        }
    }
    __syncthreads();
    const float g = lng[t], b = lnb[t];
    #pragma unroll
    for (int n = 0; n < NPB; n++) {
        float v = (acc[n] - smu[n]) * srs[n] * g + b;
        v = fmaxf(v, 0.f) + sh[n * HID + t];
        h[(size_t)(node0 + n) * HID + t] = v;
    }
}

// ---------------- pooling ----------------

__global__ void pool_init(float* __restrict__ sums, unsigned* __restrict__ maxu,
                          int* __restrict__ counts) {
    int i = blockIdx.x * blockDim.x + threadIdx.x;
    if (i < N_GRAPHS * HID) { sums[i] = 0.f; maxu[i] = 0x007FFFFFu; /* encoded -inf */ }
    if (i < N_GRAPHS) counts[i] = 0;
}

__global__ __launch_bounds__(128) void pool_accum(const float* __restrict__ h,
                                                  const int* __restrict__ batch,
                                                  float* __restrict__ sums,
                                                  unsigned* __restrict__ maxu,
                                                  int* __restrict__ counts) {
    const int node = blockIdx.x, t = threadIdx.x;
    const int b = batch[node];
    const float v = h[(size_t)node * HID + t];
    atomicAdd(&sums[b * HID + t], v);
    unsigned u = __float_as_uint(v);
    unsigned key = (u & 0x80000000u) ? ~u : (u | 0x80000000u);
    atomicMax(&maxu[b * HID + t], key);
    if (t == 0) atomicAdd(&counts[b], 1);
}

__global__ __launch_bounds__(128) void readout(const float* __restrict__ sums,
                                               const unsigned* __restrict__ maxu,
                                               const int* __restrict__ counts,
                                               const float* __restrict__ w1,
                                               const float* __restrict__ b1,
                                               const float* __restrict__ w2,
                                               const float* __restrict__ b2,
                                               float* __restrict__ out) {
    __shared__ float g[2 * HID];
    __shared__ float red[2];
    const int t = threadIdx.x, gi = blockIdx.x;
    const float c = fmaxf((float)counts[gi], 1.f);
    g[t] = sums[gi * HID + t] / c;
    unsigned key = maxu[gi * HID + t];
    unsigned u = (key & 0x80000000u) ? (key ^ 0x80000000u) : ~key;
    g[HID + t] = __uint_as_float(u);
    __syncthreads();
    float acc = b1[t];
    for (int k = 0; k < 2 * HID; k++) acc += g[k] * w1[k * HID + t];
    float s = fmaxf(acc, 0.f) * w2[t];
    s += __shfl_down(s, 32); s += __shfl_down(s, 16); s += __shfl_down(s, 8);
    s += __shfl_down(s, 4);  s += __shfl_down(s, 2);  s += __shfl_down(s, 1);
    if ((t & 63) == 0) red[t >> 6] = s;
    __syncthreads();
    if (t == 0) out[gi] = red[0] + red[1] + b2[0];
}

// ---------------- launch ----------------

extern "C" void kernel_launch(void* const* d_in, const int* in_sizes, int n_in,
                              void* d_out, int out_size, void* d_ws, size_t ws_size,
                              hipStream_t stream) {
    const float* x           = (const float*)d_in[0];
    const int*   edge_index  = (const int*)  d_in[1];
    const float* edge_attr   = (const float*)d_in[2];
    const int*   batch       = (const int*)  d_in[3];
    const float* node_proj_w = (const float*)d_in[4];
    const float* node_proj_b = (const float*)d_in[5];
    const float* msg_w1      = (const float*)d_in[6];
    const float* msg_b1      = (const float*)d_in[7];
    const float* msg_w2      = (const float*)d_in[8];
    const float* msg_b2      = (const float*)d_in[9];
    const float* upd_w       = (const float*)d_in[10];
    const float* upd_b       = (const float*)d_in[11];
    const float* ln_g        = (const float*)d_in[12];
    const float* ln_b        = (const float*)d_in[13];
    const float* ffn_w1      = (const float*)d_in[14];
    const float* ffn_b1      = (const float*)d_in[15];
    const float* ffn_w2      = (const float*)d_in[16];
    const float* ffn_b2      = (const float*)d_in[17];
    float* out = (float*)d_out;

    char* ws = (char*)d_ws;
    size_t off = 0;
    auto alloc = [&](size_t b) -> char* {
        char* p = ws + off;
        off = (off + b + 255) & ~(size_t)255;
        return p;
    };
    float*    h       = (float*)alloc((size_t)N_NODES * HID * 4);
    float*    npart   = (float*)alloc((size_t)N_NODES * HID * 4);
    float*    r       = (float*)alloc((size_t)N_NODES * HID * 4);
    float*    W2u     = (float*)alloc(HID * HID * 4);
    float*    b2u     = (float*)alloc(HID * 4);
    int*      rowptr  = (int*)alloc((N_NODES + 1) * 4);
    int*      deg     = (int*)alloc((size_t)N_NODES * 4 * 2);  // deg + cursor contiguous
    int*      cursor  = deg + N_NODES;
    int*      csr_eid = (int*)alloc((size_t)N_EDGES * 4);
    int*      csr_src = (int*)alloc((size_t)N_EDGES * 4);
    float*    sums    = (float*)alloc(N_GRAPHS * HID * 4);
    unsigned* maxu    = (unsigned*)alloc(N_GRAPHS * HID * 4);
    int*      counts  = (int*)alloc(N_GRAPHS * 4);
    (void)in_sizes; (void)n_in; (void)out_size; (void)ws_size;

    // CSR build (per call; ws is re-poisoned each launch)
    hipMemsetAsync(deg, 0, (size_t)N_NODES * 4 * 2, stream);
    hist_kernel<<<(N_EDGES + 255) / 256, 256, 0, stream>>>(edge_index + N_EDGES, deg, N_EDGES);
    scan_kernel<<<1, 1024, 0, stream>>>(deg, rowptr);
    scatter_kernel<<<(N_EDGES + 255) / 256, 256, 0, stream>>>(edge_index, rowptr, cursor,
                                                              csr_eid, csr_src, N_EDGES);
    // h = x @ node_proj_w + b
    gemm_nodes<IN_CH><<<N_NODES / 16, 128, 0, stream>>>(x, node_proj_w, node_proj_b, h);

    for (int l = 0; l < N_LAYERS; l++) {
        const float* mw1 = msg_w1 + (size_t)l * (HID + EDGE_DIM) * HID;
        w2u_kernel<<<HID + 1, HID, 0, stream>>>(msg_w2 + (size_t)l * HID * HID,
                                                msg_b2 + l * HID,
                                                upd_w + (size_t)l * 2 * HID * HID + HID * HID,
                                                W2u, b2u);
        // nodepart = h @ msg_w1[:128] + msg_b1   (per-node part of message MLP layer 1)
        gemm_nodes<HID><<<N_NODES / 16, 128, 0, stream>>>(h, mw1, msg_b1 + l * HID, npart);
        // r[n] = sum_{e->n} relu(nodepart[src] + edge_attr @ msg_w1[128:144])
        edge_aggr<<<N_NODES, 128, 0, stream>>>(npart, mw1 + HID * HID, edge_attr,
                                               rowptr, csr_eid, csr_src, r);
        // h = relu(LN(relu(h@Wu_top + r@W2u + ub + deg*b2u))) + h
        update_nodes<<<N_NODES / 16, 128, 0, stream>>>(h, r, deg,
                                                       upd_w + (size_t)l * 2 * HID * HID,
                                                       W2u, upd_b + l * HID, b2u,
                                                       ln_g + l * HID, ln_b + l * HID);
    }

    pool_init<<<128, 128, 0, stream>>>(sums, maxu, counts);
    pool_accum<<<N_NODES, 128, 0, stream>>>(h, batch, sums, maxu, counts);
    readout<<<N_GRAPHS, 128, 0, stream>>>(sums, maxu, counts, ffn_w1, ffn_b1,
                                          ffn_w2, ffn_b2, out);
}

// Round 3
// 834.075 us; speedup vs baseline: 1.0077x; 1.0077x over previous
//
#include <hip/hip_runtime.h>
#include <hip/hip_fp16.h>
#include <math.h>

#define N_NODES 20000
#define N_EDGES 640000
#define IN_CH 64
#define EDGE_DIM 16
#define HID 128
#define N_LAYERS 3
#define N_GRAPHS 128

static_assert(N_NODES % 16 == 0, "NPB tiling");

// ---------------- CSR build ----------------

__global__ void hist_kernel(const int* __restrict__ dst, int* __restrict__ deg, int n) {
    int i = blockIdx.x * blockDim.x + threadIdx.x;
    if (i < n) atomicAdd(&deg[dst[i]], 1);
}

// exclusive prefix sum over N_NODES degrees -> rowptr[N_NODES+1]
__global__ __launch_bounds__(1024) void scan_kernel(const int* __restrict__ deg,
                                                    int* __restrict__ rowptr) {
    __shared__ int buf[1024];
    const int t = threadIdx.x;
    constexpr int PER = 20;           // 1024*20 >= 20000
    const int base = t * PER;
    int loc[PER];
    int s = 0;
    #pragma unroll
    for (int i = 0; i < PER; i++) {
        int v = (base + i < N_NODES) ? deg[base + i] : 0;
        loc[i] = s; s += v;
    }
    buf[t] = s;
    __syncthreads();
    for (int off = 1; off < 1024; off <<= 1) {
        int x = (t >= off) ? buf[t - off] : 0;
        __syncthreads();
        buf[t] += x;
        __syncthreads();
    }
    const int excl = (t == 0) ? 0 : buf[t - 1];
    #pragma unroll
    for (int i = 0; i < PER; i++)
        if (base + i < N_NODES) rowptr[base + i] = excl + loc[i];
    if (t == 1023) rowptr[N_NODES] = buf[1023];
}

__global__ void scatter_kernel(const int* __restrict__ ei, const int* __restrict__ rowptr,
                               int* __restrict__ cursor, int* __restrict__ csr_eid,
                               int* __restrict__ csr_src, int n) {
    int e = blockIdx.x * blockDim.x + threadIdx.x;
    if (e < n) {
        int d = ei[N_EDGES + e];
        int pos = atomicAdd(&cursor[d], 1);
        int slot = rowptr[d] + pos;
        csr_eid[slot] = e;
        csr_src[slot] = ei[e];
    }
}

// permute edge_attr into CSR slot order, f32 -> f16.  4 threads per edge.
__global__ __launch_bounds__(256) void permute_eattr(const float* __restrict__ ea,
                                                     const int* __restrict__ csr_eid,
                                                     __half* __restrict__ out) {
    const int slot = blockIdx.x * 64 + (threadIdx.x >> 2);
    const int c = threadIdx.x & 3;
    if (slot < N_EDGES) {
        const int e = csr_eid[slot];
        const float4 v = *(const float4*)(ea + (size_t)e * EDGE_DIM + c * 4);
        union { __half2 h[2]; uint2 u; } pk;
        pk.h[0] = __floats2half2_rn(v.x, v.y);
        pk.h[1] = __floats2half2_rn(v.z, v.w);
        *(uint2*)(out + (size_t)slot * EDGE_DIM + c * 4) = pk.u;
    }
}

// ---------------- node GEMM: out[N,128] = in[N,KIN] @ W[KIN,128] + bias ----------------

template<int KIN, bool HALF_OUT>
__global__ __launch_bounds__(128) void gemm_nodes(const float* __restrict__ in,
                                                  const float* __restrict__ W,
                                                  const float* __restrict__ bias,
                                                  void* __restrict__ outp) {
    constexpr int NPB = 16;
    __shared__ __align__(16) float a[NPB * KIN];
    const int t = threadIdx.x;
    const int node0 = blockIdx.x * NPB;
    const float* src = in + (size_t)node0 * KIN;
    #pragma unroll
    for (int i = t * 4; i < NPB * KIN; i += 512)
        *(float4*)(a + i) = *(const float4*)(src + i);
    __syncthreads();
    float acc[NPB];
    const float bv = bias[t];
    #pragma unroll
    for (int n = 0; n < NPB; n++) acc[n] = bv;
    for (int k = 0; k < KIN; k += 4) {
        const float w0 = W[(k + 0) * HID + t];
        const float w1 = W[(k + 1) * HID + t];
        const float w2 = W[(k + 2) * HID + t];
        const float w3 = W[(k + 3) * HID + t];
        #pragma unroll
        for (int n = 0; n < NPB; n++) {
            const float4 av = *(const float4*)(a + n * KIN + k);
            acc[n] += av.x * w0 + av.y * w1 + av.z * w2 + av.w * w3;
        }
    }
    if (HALF_OUT) {
        __half* o = (__half*)outp + (size_t)node0 * HID + t;
        #pragma unroll
        for (int n = 0; n < NPB; n++) o[n * HID] = __float2half(acc[n]);
    } else {
        float* o = (float*)outp + (size_t)node0 * HID + t;
        #pragma unroll
        for (int n = 0; n < NPB; n++) o[n * HID] = acc[n];
    }
}

// ---------------- combined W2u = msg_w2 @ upd_w_bottom ----------------

__global__ __launch_bounds__(128) void w2u_kernel(const float* __restrict__ w2,
                                                  const float* __restrict__ b2,
                                                  const float* __restrict__ wu_bot,
                                                  float* __restrict__ W2u,
                                                  float* __restrict__ b2u) {
    __shared__ float row[HID];
    const int t = threadIdx.x, d = blockIdx.x;
    const float* src = (d < HID) ? (w2 + d * HID) : b2;
    row[t] = src[t];
    __syncthreads();
    float acc = 0.f;
    for (int k = 0; k < HID; k++) acc += row[k] * wu_bot[k * HID + t];
    if (d < HID) W2u[d * HID + t] = acc;
    else b2u[t] = acc;
}

// -------- edge aggregate: r[n] = sum_{e: dst=n} relu(npart[src] + ea@W1e) --------
// 4 waves per block; each wave processes one edge at a time (64 lanes x half2 = 128 ch).

__global__ __launch_bounds__(256) void edge_aggr2(const __half* __restrict__ npart,
                                                  const float* __restrict__ W1e,
                                                  const __half* __restrict__ eattr,
                                                  const int* __restrict__ rowptr,
                                                  const int* __restrict__ csr_src,
                                                  float* __restrict__ r) {
    const int node = blockIdx.x;
    const int t = threadIdx.x;
    const int w = t >> 6, l = t & 63;
    float wk0[EDGE_DIM], wk1[EDGE_DIM];
    #pragma unroll
    for (int k = 0; k < EDGE_DIM; k++) {
        wk0[k] = W1e[k * HID + 2 * l];
        wk1[k] = W1e[k * HID + 2 * l + 1];
    }
    const int beg = rowptr[node], end = rowptr[node + 1];
    float acc0 = 0.f, acc1 = 0.f;
    int i = beg + w;
    int s = (i < end) ? csr_src[i] : 0;
    while (i < end) {
        const __half2 hv = *(const __half2*)(npart + (size_t)s * HID + 2 * l);
        union { uint4 u; __half2 h[4]; } ua, ub;
        ua.u = *(const uint4*)(eattr + (size_t)i * EDGE_DIM);      // ea[0..7]
        ub.u = *(const uint4*)(eattr + (size_t)i * EDGE_DIM + 8);  // ea[8..15]
        const int inext = i + 4;
        const int snext = (inext < end) ? csr_src[inext] : 0;      // prefetch src idx
        const float2 hz = __half22float2(hv);
        float z0 = hz.x, z1 = hz.y;
        #pragma unroll
        for (int j = 0; j < 4; j++) {
            const float2 e2 = __half22float2(ua.h[j]);
            z0 += e2.x * wk0[2 * j] + e2.y * wk0[2 * j + 1];
            z1 += e2.x * wk1[2 * j] + e2.y * wk1[2 * j + 1];
        }
        #pragma unroll
        for (int j = 0; j < 4; j++) {
            const float2 e2 = __half22float2(ub.h[j]);
            z0 += e2.x * wk0[8 + 2 * j] + e2.y * wk0[8 + 2 * j + 1];
            z1 += e2.x * wk1[8 + 2 * j] + e2.y * wk1[8 + 2 * j + 1];
        }
        acc0 += fmaxf(z0, 0.f);
        acc1 += fmaxf(z1, 0.f);
        i = inext; s = snext;
    }
    __shared__ float part[4][HID];
    *(float2*)&part[w][2 * l] = make_float2(acc0, acc1);
    __syncthreads();
    if (t < HID)
        r[(size_t)node * HID + t] = part[0][t] + part[1][t] + part[2][t] + part[3][t];
}

// ---------------- fused update + LayerNorm + relu + residual (in-place on h) ----------------

__global__ __launch_bounds__(128) void update_nodes(float* __restrict__ h,
                                                    const float* __restrict__ r,
                                                    const int* __restrict__ deg,
                                                    const float* __restrict__ Wt,
                                                    const float* __restrict__ W2u,
                                                    const float* __restrict__ ub,
                                                    const float* __restrict__ b2u,
                                                    const float* __restrict__ lng,
                                                    const float* __restrict__ lnb) {
    constexpr int NPB = 16;
    __shared__ __align__(16) float sh[NPB * HID];
    __shared__ __align__(16) float sr[NPB * HID];
    __shared__ float smu[NPB], srs[NPB];
    const int t = threadIdx.x;
    const int node0 = blockIdx.x * NPB;
    #pragma unroll
    for (int i = t * 4; i < NPB * HID; i += 512) {
        *(float4*)(sh + i) = *(const float4*)(h + (size_t)node0 * HID + i);
        *(float4*)(sr + i) = *(const float4*)(r + (size_t)node0 * HID + i);
    }
    __syncthreads();
    float acc[NPB];
    const float ubv = ub[t], b2uv = b2u[t];
    #pragma unroll
    for (int n = 0; n < NPB; n++) acc[n] = ubv + (float)deg[node0 + n] * b2uv;
    for (int k = 0; k < HID; k += 4) {
        const float wt0 = Wt[(k + 0) * HID + t], w20 = W2u[(k + 0) * HID + t];
        const float wt1 = Wt[(k + 1) * HID + t], w21 = W2u[(k + 1) * HID + t];
        const float wt2 = Wt[(k + 2) * HID + t], w22 = W2u[(k + 2) * HID + t];
        const float wt3 = Wt[(k + 3) * HID + t], w23 = W2u[(k + 3) * HID + t];
        #pragma unroll
        for (int n = 0; n < NPB; n++) {
            const float4 hv = *(const float4*)(sh + n * HID + k);
            const float4 rv = *(const float4*)(sr + n * HID + k);
            acc[n] += hv.x * wt0 + hv.y * wt1 + hv.z * wt2 + hv.w * wt3;
            acc[n] += rv.x * w20 + rv.y * w21 + rv.z * w22 + rv.w * w23;
        }
    }
    #pragma unroll
    for (int n = 0; n < NPB; n++) acc[n] = fmaxf(acc[n], 0.f);   // u = relu(...)
    __syncthreads();                 // done reading sr
    #pragma unroll
    for (int n = 0; n < NPB; n++) sr[n * HID + t] = acc[n];
    __syncthreads();
    // LayerNorm stats: 8 threads per node
    {
        const int n = t >> 3, lane = t & 7;
        float s = 0.f, ss = 0.f;
        #pragma unroll
        for (int i = 0; i < 16; i++) {
            float v = sr[n * HID + lane + i * 8];
            s += v; ss += v * v;
        }
        s += __shfl_xor(s, 1); ss += __shfl_xor(ss, 1);
        s += __shfl_xor(s, 2); ss += __shfl_xor(ss, 2);
        s += __shfl_xor(s, 4); ss += __shfl_xor(ss, 4);
        if (lane == 0) {
            float mu = s * (1.f / HID);
            float var = ss * (1.f / HID) - mu * mu;
            smu[n] = mu;
            srs[n] = rsqrtf(var + 1e-5f);
        }
    }
    __syncthreads();
    const float g = lng[t], b = lnb[t];
    #pragma unroll
    for (int n = 0; n < NPB; n++) {
        float v = (acc[n] - smu[n]) * srs[n] * g + b;
        v = fmaxf(v, 0.f) + sh[n * HID + t];
        h[(size_t)(node0 + n) * HID + t] = v;
    }
}

// ---------------- pooling ----------------

__global__ void pool_init(float* __restrict__ sums, unsigned* __restrict__ maxu,
                          int* __restrict__ counts) {
    int i = blockIdx.x * blockDim.x + threadIdx.x;
    if (i < N_GRAPHS * HID) { sums[i] = 0.f; maxu[i] = 0x007FFFFFu; /* encoded -inf */ }
    if (i < N_GRAPHS) counts[i] = 0;
}

__global__ __launch_bounds__(128) void pool_accum(const float* __restrict__ h,
                                                  const int* __restrict__ batch,
                                                  float* __restrict__ sums,
                                                  unsigned* __restrict__ maxu,
                                                  int* __restrict__ counts) {
    const int node = blockIdx.x, t = threadIdx.x;
    const int b = batch[node];
    const float v = h[(size_t)node * HID + t];
    atomicAdd(&sums[b * HID + t], v);
    unsigned u = __float_as_uint(v);
    unsigned key = (u & 0x80000000u) ? ~u : (u | 0x80000000u);
    atomicMax(&maxu[b * HID + t], key);
    if (t == 0) atomicAdd(&counts[b], 1);
}

__global__ __launch_bounds__(128) void readout(const float* __restrict__ sums,
                                               const unsigned* __restrict__ maxu,
                                               const int* __restrict__ counts,
                                               const float* __restrict__ w1,
                                               const float* __restrict__ b1,
                                               const float* __restrict__ w2,
                                               const float* __restrict__ b2,
                                               float* __restrict__ out) {
    __shared__ float g[2 * HID];
    __shared__ float red[2];
    const int t = threadIdx.x, gi = blockIdx.x;
    const float c = fmaxf((float)counts[gi], 1.f);
    g[t] = sums[gi * HID + t] / c;
    unsigned key = maxu[gi * HID + t];
    unsigned u = (key & 0x80000000u) ? (key ^ 0x80000000u) : ~key;
    g[HID + t] = __uint_as_float(u);
    __syncthreads();
    float acc = b1[t];
    for (int k = 0; k < 2 * HID; k++) acc += g[k] * w1[k * HID + t];
    float s = fmaxf(acc, 0.f) * w2[t];
    s += __shfl_down(s, 32); s += __shfl_down(s, 16); s += __shfl_down(s, 8);
    s += __shfl_down(s, 4);  s += __shfl_down(s, 2);  s += __shfl_down(s, 1);
    if ((t & 63) == 0) red[t >> 6] = s;
    __syncthreads();
    if (t == 0) out[gi] = red[0] + red[1] + b2[0];
}

// ---------------- launch ----------------

extern "C" void kernel_launch(void* const* d_in, const int* in_sizes, int n_in,
                              void* d_out, int out_size, void* d_ws, size_t ws_size,
                              hipStream_t stream) {
    const float* x           = (const float*)d_in[0];
    const int*   edge_index  = (const int*)  d_in[1];
    const float* edge_attr   = (const float*)d_in[2];
    const int*   batch       = (const int*)  d_in[3];
    const float* node_proj_w = (const float*)d_in[4];
    const float* node_proj_b = (const float*)d_in[5];
    const float* msg_w1      = (const float*)d_in[6];
    const float* msg_b1      = (const float*)d_in[7];
    const float* msg_w2      = (const float*)d_in[8];
    const float* msg_b2      = (const float*)d_in[9];
    const float* upd_w       = (const float*)d_in[10];
    const float* upd_b       = (const float*)d_in[11];
    const float* ln_g        = (const float*)d_in[12];
    const float* ln_b        = (const float*)d_in[13];
    const float* ffn_w1      = (const float*)d_in[14];
    const float* ffn_b1      = (const float*)d_in[15];
    const float* ffn_w2      = (const float*)d_in[16];
    const float* ffn_b2      = (const float*)d_in[17];
    float* out = (float*)d_out;

    char* ws = (char*)d_ws;
    size_t off = 0;
    auto alloc = [&](size_t b) -> char* {
        char* p = ws + off;
        off = (off + b + 255) & ~(size_t)255;
        return p;
    };
    float*    h       = (float*)alloc((size_t)N_NODES * HID * 4);
    __half*   npart_h = (__half*)alloc((size_t)N_NODES * HID * 2);
    float*    r       = (float*)alloc((size_t)N_NODES * HID * 4);
    float*    W2u     = (float*)alloc(HID * HID * 4);
    float*    b2u     = (float*)alloc(HID * 4);
    int*      rowptr  = (int*)alloc((N_NODES + 1) * 4);
    int*      deg     = (int*)alloc((size_t)N_NODES * 4 * 2);  // deg + cursor contiguous
    int*      cursor  = deg + N_NODES;
    int*      csr_eid = (int*)alloc((size_t)N_EDGES * 4);
    int*      csr_src = (int*)alloc((size_t)N_EDGES * 4);
    __half*   eattr_h = (__half*)alloc((size_t)N_EDGES * EDGE_DIM * 2);
    float*    sums    = (float*)alloc(N_GRAPHS * HID * 4);
    unsigned* maxu    = (unsigned*)alloc(N_GRAPHS * HID * 4);
    int*      counts  = (int*)alloc(N_GRAPHS * 4);
    (void)in_sizes; (void)n_in; (void)out_size; (void)ws_size;

    // CSR build (per call; ws is re-poisoned each launch)
    hipMemsetAsync(deg, 0, (size_t)N_NODES * 4 * 2, stream);
    hist_kernel<<<(N_EDGES + 255) / 256, 256, 0, stream>>>(edge_index + N_EDGES, deg, N_EDGES);
    scan_kernel<<<1, 1024, 0, stream>>>(deg, rowptr);
    scatter_kernel<<<(N_EDGES + 255) / 256, 256, 0, stream>>>(edge_index, rowptr, cursor,
                                                              csr_eid, csr_src, N_EDGES);
    // edge_attr -> CSR order, fp16 (reused by all 3 layers)
    permute_eattr<<<N_EDGES / 64, 256, 0, stream>>>(edge_attr, csr_eid, eattr_h);
    // h = x @ node_proj_w + b
    gemm_nodes<IN_CH, false><<<N_NODES / 16, 128, 0, stream>>>(x, node_proj_w, node_proj_b, h);

    for (int l = 0; l < N_LAYERS; l++) {
        const float* mw1 = msg_w1 + (size_t)l * (HID + EDGE_DIM) * HID;
        w2u_kernel<<<HID + 1, HID, 0, stream>>>(msg_w2 + (size_t)l * HID * HID,
                                                msg_b2 + l * HID,
                                                upd_w + (size_t)l * 2 * HID * HID + HID * HID,
                                                W2u, b2u);
        // nodepart = h @ msg_w1[:128] + msg_b1  (fp16, gathered per edge)
        gemm_nodes<HID, true><<<N_NODES / 16, 128, 0, stream>>>(h, mw1, msg_b1 + l * HID, npart_h);
        // r[n] = sum_{e->n} relu(nodepart[src] + edge_attr @ msg_w1[128:144])
        edge_aggr2<<<N_NODES, 256, 0, stream>>>(npart_h, mw1 + HID * HID, eattr_h,
                                                rowptr, csr_src, r);
        // h = relu(LN(relu(h@Wu_top + r@W2u + ub + deg*b2u))) + h
        update_nodes<<<N_NODES / 16, 128, 0, stream>>>(h, r, deg,
                                                       upd_w + (size_t)l * 2 * HID * HID,
                                                       W2u, upd_b + l * HID, b2u,
                                                       ln_g + l * HID, ln_b + l * HID);
    }

    pool_init<<<128, 128, 0, stream>>>(sums, maxu, counts);
    pool_accum<<<N_NODES, 128, 0, stream>>>(h, batch, sums, maxu, counts);
    readout<<<N_GRAPHS, 128, 0, stream>>>(sums, maxu, counts, ffn_w1, ffn_b1,
                                          ffn_w2, ffn_b2, out);
}

// Round 4
// 685.650 us; speedup vs baseline: 1.2259x; 1.2165x over previous
//
#include <hip/hip_runtime.h>
#include <hip/hip_fp16.h>
#include <math.h>

#define N_NODES 20000
#define N_EDGES 640000
#define IN_CH 64
#define EDGE_DIM 16
#define HID 128
#define N_LAYERS 3
#define N_GRAPHS 128

typedef _Float16 h2 __attribute__((ext_vector_type(2)));

__device__ inline float fdot2f(h2 a, h2 b, float c) {
#if __has_builtin(__builtin_amdgcn_fdot2)
    return __builtin_amdgcn_fdot2(a, b, c, false);
#else
    float d;
    asm("v_dot2_f32_f16 %0, %1, %2, %3" : "=v"(d) : "v"(a), "v"(b), "v"(c));
    return d;
#endif
}

// ---------------- CSR build ----------------

__global__ void hist_kernel(const int* __restrict__ dst, int* __restrict__ deg, int n) {
    int i = blockIdx.x * blockDim.x + threadIdx.x;
    if (i < n) atomicAdd(&deg[dst[i]], 1);
}

__global__ __launch_bounds__(1024) void scan_kernel(const int* __restrict__ deg,
                                                    int* __restrict__ rowptr) {
    __shared__ int buf[1024];
    const int t = threadIdx.x;
    constexpr int PER = 20;           // 1024*20 >= 20000
    const int base = t * PER;
    int loc[PER];
    int s = 0;
    #pragma unroll
    for (int i = 0; i < PER; i++) {
        int v = (base + i < N_NODES) ? deg[base + i] : 0;
        loc[i] = s; s += v;
    }
    buf[t] = s;
    __syncthreads();
    for (int off = 1; off < 1024; off <<= 1) {
        int x = (t >= off) ? buf[t - off] : 0;
        __syncthreads();
        buf[t] += x;
        __syncthreads();
    }
    const int excl = (t == 0) ? 0 : buf[t - 1];
    #pragma unroll
    for (int i = 0; i < PER; i++)
        if (base + i < N_NODES) rowptr[base + i] = excl + loc[i];
    if (t == 1023) rowptr[N_NODES] = buf[1023];
}

// scatter: assign CSR slot, write src index AND fp16 edge_attr directly into slot order
__global__ __launch_bounds__(256) void scatter_kernel(const int* __restrict__ ei,
                                                      const float* __restrict__ ea,
                                                      const int* __restrict__ rowptr,
                                                      int* __restrict__ cursor,
                                                      int* __restrict__ csr_src,
                                                      __half* __restrict__ eattr, int n) {
    int e = blockIdx.x * blockDim.x + threadIdx.x;
    if (e < n) {
        int d = ei[N_EDGES + e];
        int pos = atomicAdd(&cursor[d], 1);
        int slot = rowptr[d] + pos;
        csr_src[slot] = ei[e];
        const float4* s4 = (const float4*)(ea + (size_t)e * EDGE_DIM);
        const float4 a = s4[0], b = s4[1], c = s4[2], dd = s4[3];
        union { uint4 u; __half2 h[4]; } p0, p1;
        p0.h[0] = __floats2half2_rn(a.x, a.y);  p0.h[1] = __floats2half2_rn(a.z, a.w);
        p0.h[2] = __floats2half2_rn(b.x, b.y);  p0.h[3] = __floats2half2_rn(b.z, b.w);
        p1.h[0] = __floats2half2_rn(c.x, c.y);  p1.h[1] = __floats2half2_rn(c.z, c.w);
        p1.h[2] = __floats2half2_rn(dd.x, dd.y); p1.h[3] = __floats2half2_rn(dd.z, dd.w);
        uint4* o = (uint4*)(eattr + (size_t)slot * EDGE_DIM);
        o[0] = p0.u; o[1] = p1.u;
    }
}

// pack W1e (edge part of msg_w1) into half2 pairs: pk[l][j][c>>1][c&1] = (W[2j][c], W[2j+1][c])
__global__ __launch_bounds__(128) void prep_w1e(const float* __restrict__ msg_w1,
                                                __half2* __restrict__ pk) {
    const int l = blockIdx.x, c = threadIdx.x;
    const float* W1e = msg_w1 + (size_t)l * (HID + EDGE_DIM) * HID + HID * HID;
    #pragma unroll
    for (int j = 0; j < 8; j++) {
        __half2 v = __floats2half2_rn(W1e[(2 * j) * HID + c], W1e[(2 * j + 1) * HID + c]);
        pk[((l * 8 + j) * 64 + (c >> 1)) * 2 + (c & 1)] = v;
    }
}

// ---------------- node GEMM: out[N,128] = in[N,KIN] @ W[KIN,128] + bias ----------------

template<int KIN, bool HALF_OUT>
__global__ __launch_bounds__(128) void gemm_nodes(const float* __restrict__ in,
                                                  const float* __restrict__ W,
                                                  const float* __restrict__ bias,
                                                  void* __restrict__ outp) {
    constexpr int NPB = 16;
    __shared__ __align__(16) float a[NPB * KIN];
    const int t = threadIdx.x;
    const int node0 = blockIdx.x * NPB;
    const float* src = in + (size_t)node0 * KIN;
    #pragma unroll
    for (int i = t * 4; i < NPB * KIN; i += 512)
        *(float4*)(a + i) = *(const float4*)(src + i);
    __syncthreads();
    float acc[NPB];
    const float bv = bias[t];
    #pragma unroll
    for (int n = 0; n < NPB; n++) acc[n] = bv;
    for (int k = 0; k < KIN; k += 4) {
        const float w0 = W[(k + 0) * HID + t];
        const float w1 = W[(k + 1) * HID + t];
        const float w2 = W[(k + 2) * HID + t];
        const float w3 = W[(k + 3) * HID + t];
        #pragma unroll
        for (int n = 0; n < NPB; n++) {
            const float4 av = *(const float4*)(a + n * KIN + k);
            acc[n] += av.x * w0 + av.y * w1 + av.z * w2 + av.w * w3;
        }
    }
    if (HALF_OUT) {
        __half* o = (__half*)outp + (size_t)node0 * HID + t;
        #pragma unroll
        for (int n = 0; n < NPB; n++) o[n * HID] = __float2half(acc[n]);
    } else {
        float* o = (float*)outp + (size_t)node0 * HID + t;
        #pragma unroll
        for (int n = 0; n < NPB; n++) o[n * HID] = acc[n];
    }
}

// ---------------- combined W2u = msg_w2 @ upd_w_bottom, all layers ----------------

__global__ __launch_bounds__(128) void w2u_all(const float* __restrict__ msg_w2,
                                               const float* __restrict__ msg_b2,
                                               const float* __restrict__ upd_w,
                                               float* __restrict__ W2u,
                                               float* __restrict__ b2u) {
    __shared__ float row[HID];
    const int t = threadIdx.x;
    const int l = blockIdx.x / 129, d = blockIdx.x % 129;
    const float* w2 = msg_w2 + (size_t)l * HID * HID;
    const float* wu_bot = upd_w + (size_t)l * 2 * HID * HID + HID * HID;
    const float* src = (d < HID) ? (w2 + d * HID) : (msg_b2 + l * HID);
    row[t] = src[t];
    __syncthreads();
    float acc = 0.f;
    for (int k = 0; k < HID; k++) acc += row[k] * wu_bot[k * HID + t];
    if (d < HID) W2u[(size_t)l * HID * HID + d * HID + t] = acc;
    else b2u[l * HID + t] = acc;
}

// -------- edge aggregate: r[n] = sum_{e: dst=n} relu(npart[src] + ea@W1e) --------
// 8 nodes per block; 4 waves; each wave processes 2 edges per iteration via v_dot2_f32_f16.

#define EA_NPB 8

__global__ __launch_bounds__(256) void edge_aggr3(const __half* __restrict__ npart,
                                                  const __half2* __restrict__ w1epk,
                                                  const __half* __restrict__ eattr,
                                                  const int* __restrict__ rowptr,
                                                  const int* __restrict__ csr_src,
                                                  float* __restrict__ r) {
    const int t = threadIdx.x;
    const int w = t >> 6, l = t & 63;
    h2 wk0[8], wk1[8];
    const uint2* wp = (const uint2*)w1epk;
    #pragma unroll
    for (int j = 0; j < 8; j++) {
        union { uint u; h2 h; } q0, q1;
        const uint2 q = wp[j * 64 + l];
        q0.u = q.x; q1.u = q.y;
        wk0[j] = q0.h; wk1[j] = q1.h;
    }
    __shared__ float part[4][HID];
    const int node0 = blockIdx.x * EA_NPB;
    for (int nn = 0; nn < EA_NPB; nn++) {
        const int node = node0 + nn;
        const int beg = rowptr[node], end = rowptr[node + 1];
        float acc0 = 0.f, acc1 = 0.f;
        for (int i = beg + 2 * w; i < end; i += 8) {
            const int i1 = i + 1;
            const bool has2 = (i1 < end);
            const int s0 = csr_src[i];
            const int s1 = has2 ? csr_src[i1] : s0;
            const h2 hv0 = *(const h2*)(npart + (size_t)s0 * HID + 2 * l);
            const h2 hv1 = *(const h2*)(npart + (size_t)s1 * HID + 2 * l);
            union { uint4 u; h2 h[4]; } a0, b0, a1, b1;
            const uint4* e0 = (const uint4*)(eattr + (size_t)i * EDGE_DIM);
            a0.u = e0[0]; b0.u = e0[1];
            const uint4* e1 = (const uint4*)(eattr + (size_t)(has2 ? i1 : i) * EDGE_DIM);
            a1.u = e1[0]; b1.u = e1[1];
            float z00 = (float)hv0.x, z01 = (float)hv0.y;
            float z10 = (float)hv1.x, z11 = (float)hv1.y;
            #pragma unroll
            for (int j = 0; j < 4; j++) {
                z00 = fdot2f(a0.h[j], wk0[j], z00);
                z01 = fdot2f(a0.h[j], wk1[j], z01);
                z10 = fdot2f(a1.h[j], wk0[j], z10);
                z11 = fdot2f(a1.h[j], wk1[j], z11);
            }
            #pragma unroll
            for (int j = 0; j < 4; j++) {
                z00 = fdot2f(b0.h[j], wk0[4 + j], z00);
                z01 = fdot2f(b0.h[j], wk1[4 + j], z01);
                z10 = fdot2f(b1.h[j], wk0[4 + j], z10);
                z11 = fdot2f(b1.h[j], wk1[4 + j], z11);
            }
            acc0 += fmaxf(z00, 0.f);
            acc1 += fmaxf(z01, 0.f);
            if (has2) { acc0 += fmaxf(z10, 0.f); acc1 += fmaxf(z11, 0.f); }
        }
        *(float2*)&part[w][2 * l] = make_float2(acc0, acc1);
        __syncthreads();
        if (t < HID)
            r[(size_t)node * HID + t] = part[0][t] + part[1][t] + part[2][t] + part[3][t];
        __syncthreads();
    }
}

// ---------------- fused update + LayerNorm + relu + residual (in-place on h) ----------------

__global__ __launch_bounds__(128) void update_nodes(float* __restrict__ h,
                                                    const float* __restrict__ r,
                                                    const int* __restrict__ deg,
                                                    const float* __restrict__ Wt,
                                                    const float* __restrict__ W2u,
                                                    const float* __restrict__ ub,
                                                    const float* __restrict__ b2u,
                                                    const float* __restrict__ lng,
                                                    const float* __restrict__ lnb) {
    constexpr int NPB = 16;
    __shared__ __align__(16) float sh[NPB * HID];
    __shared__ __align__(16) float sr[NPB * HID];
    __shared__ float smu[NPB], srs[NPB];
    const int t = threadIdx.x;
    const int node0 = blockIdx.x * NPB;
    #pragma unroll
    for (int i = t * 4; i < NPB * HID; i += 512) {
        *(float4*)(sh + i) = *(const float4*)(h + (size_t)node0 * HID + i);
        *(float4*)(sr + i) = *(const float4*)(r + (size_t)node0 * HID + i);
    }
    __syncthreads();
    float acc[NPB];
    const float ubv = ub[t], b2uv = b2u[t];
    #pragma unroll
    for (int n = 0; n < NPB; n++) acc[n] = ubv + (float)deg[node0 + n] * b2uv;
    for (int k = 0; k < HID; k += 4) {
        const float wt0 = Wt[(k + 0) * HID + t], w20 = W2u[(k + 0) * HID + t];
        const float wt1 = Wt[(k + 1) * HID + t], w21 = W2u[(k + 1) * HID + t];
        const float wt2 = Wt[(k + 2) * HID + t], w22 = W2u[(k + 2) * HID + t];
        const float wt3 = Wt[(k + 3) * HID + t], w23 = W2u[(k + 3) * HID + t];
        #pragma unroll
        for (int n = 0; n < NPB; n++) {
            const float4 hv = *(const float4*)(sh + n * HID + k);
            const float4 rv = *(const float4*)(sr + n * HID + k);
            acc[n] += hv.x * wt0 + hv.y * wt1 + hv.z * wt2 + hv.w * wt3;
            acc[n] += rv.x * w20 + rv.y * w21 + rv.z * w22 + rv.w * w23;
        }
    }
    #pragma unroll
    for (int n = 0; n < NPB; n++) acc[n] = fmaxf(acc[n], 0.f);
    __syncthreads();
    #pragma unroll
    for (int n = 0; n < NPB; n++) sr[n * HID + t] = acc[n];
    __syncthreads();
    {
        const int n = t >> 3, lane = t & 7;
        float s = 0.f, ss = 0.f;
        #pragma unroll
        for (int i = 0; i < 16; i++) {
            float v = sr[n * HID + lane + i * 8];
            s += v; ss += v * v;
        }
        s += __shfl_xor(s, 1); ss += __shfl_xor(ss, 1);
        s += __shfl_xor(s, 2); ss += __shfl_xor(ss, 2);
        s += __shfl_xor(s, 4); ss += __shfl_xor(ss, 4);
        if (lane == 0) {
            float mu = s * (1.f / HID);
            float var = ss * (1.f / HID) - mu * mu;
            smu[n] = mu;
            srs[n] = rsqrtf(var + 1e-5f);
        }
    }
    __syncthreads();
    const float g = lng[t], b = lnb[t];
    #pragma unroll
    for (int n = 0; n < NPB; n++) {
        float v = (acc[n] - smu[n]) * srs[n] * g + b;
        v = fmaxf(v, 0.f) + sh[n * HID + t];
        h[(size_t)(node0 + n) * HID + t] = v;
    }
}

// ---------------- fused pooling + readout (batch is sorted -> segment scan, no atomics) ----------------

__global__ __launch_bounds__(128) void pool_readout(const float* __restrict__ h,
                                                    const int* __restrict__ batch,
                                                    const float* __restrict__ w1,
                                                    const float* __restrict__ b1,
                                                    const float* __restrict__ w2,
                                                    const float* __restrict__ b2,
                                                    float* __restrict__ out) {
    __shared__ int sbe[2];
    __shared__ float g[2 * HID];
    __shared__ float red[2];
    const int t = threadIdx.x, gi = blockIdx.x;
    if (t < 2) {
        const int target = gi + t;
        int lo = 0, hi = N_NODES;
        while (lo < hi) { int m = (lo + hi) >> 1; if (batch[m] < target) lo = m + 1; else hi = m; }
        sbe[t] = lo;
    }
    __syncthreads();
    const int beg = sbe[0], end = sbe[1];
    float sum = 0.f, mx = -INFINITY;
    int n = beg;
    for (; n + 4 <= end; n += 4) {
        const float v0 = h[(size_t)(n + 0) * HID + t];
        const float v1 = h[(size_t)(n + 1) * HID + t];
        const float v2 = h[(size_t)(n + 2) * HID + t];
        const float v3 = h[(size_t)(n + 3) * HID + t];
        sum += v0 + v1 + v2 + v3;
        mx = fmaxf(mx, fmaxf(fmaxf(v0, v1), fmaxf(v2, v3)));
    }
    for (; n < end; n++) { const float v = h[(size_t)n * HID + t]; sum += v; mx = fmaxf(mx, v); }
    const float c = fmaxf((float)(end - beg), 1.f);
    g[t] = sum / c;
    g[HID + t] = mx;
    __syncthreads();
    float acc = b1[t];
    for (int k = 0; k < 2 * HID; k++) acc += g[k] * w1[k * HID + t];
    float s = fmaxf(acc, 0.f) * w2[t];
    s += __shfl_down(s, 32); s += __shfl_down(s, 16); s += __shfl_down(s, 8);
    s += __shfl_down(s, 4);  s += __shfl_down(s, 2);  s += __shfl_down(s, 1);
    if ((t & 63) == 0) red[t >> 6] = s;
    __syncthreads();
    if (t == 0) out[gi] = red[0] + red[1] + b2[0];
}

// ---------------- launch ----------------

extern "C" void kernel_launch(void* const* d_in, const int* in_sizes, int n_in,
                              void* d_out, int out_size, void* d_ws, size_t ws_size,
                              hipStream_t stream) {
    const float* x           = (const float*)d_in[0];
    const int*   edge_index  = (const int*)  d_in[1];
    const float* edge_attr   = (const float*)d_in[2];
    const int*   batch       = (const int*)  d_in[3];
    const float* node_proj_w = (const float*)d_in[4];
    const float* node_proj_b = (const float*)d_in[5];
    const float* msg_w1      = (const float*)d_in[6];
    const float* msg_b1      = (const float*)d_in[7];
    const float* msg_w2      = (const float*)d_in[8];
    const float* msg_b2      = (const float*)d_in[9];
    const float* upd_w       = (const float*)d_in[10];
    const float* upd_b       = (const float*)d_in[11];
    const float* ln_g        = (const float*)d_in[12];
    const float* ln_b        = (const float*)d_in[13];
    const float* ffn_w1      = (const float*)d_in[14];
    const float* ffn_b1      = (const float*)d_in[15];
    const float* ffn_w2      = (const float*)d_in[16];
    const float* ffn_b2      = (const float*)d_in[17];
    float* out = (float*)d_out;

    char* ws = (char*)d_ws;
    size_t off = 0;
    auto alloc = [&](size_t b) -> char* {
        char* p = ws + off;
        off = (off + b + 255) & ~(size_t)255;
        return p;
    };
    float*    h        = (float*)alloc((size_t)N_NODES * HID * 4);
    __half*   npart_h  = (__half*)alloc((size_t)N_NODES * HID * 2);
    float*    r        = (float*)alloc((size_t)N_NODES * HID * 4);
    float*    W2u_all  = (float*)alloc((size_t)N_LAYERS * HID * HID * 4);
    float*    b2u_all  = (float*)alloc((size_t)N_LAYERS * HID * 4);
    __half2*  w1epk    = (__half2*)alloc((size_t)N_LAYERS * 8 * 64 * 2 * 4);
    int*      rowptr   = (int*)alloc((N_NODES + 1) * 4);
    int*      deg      = (int*)alloc((size_t)N_NODES * 4 * 2);  // deg + cursor contiguous
    int*      cursor   = deg + N_NODES;
    int*      csr_src  = (int*)alloc((size_t)N_EDGES * 4);
    __half*   eattr_h  = (__half*)alloc((size_t)N_EDGES * EDGE_DIM * 2);
    (void)in_sizes; (void)n_in; (void)out_size; (void)ws_size;

    // CSR build (per call; ws is re-poisoned each launch)
    hipMemsetAsync(deg, 0, (size_t)N_NODES * 4 * 2, stream);
    hist_kernel<<<(N_EDGES + 255) / 256, 256, 0, stream>>>(edge_index + N_EDGES, deg, N_EDGES);
    scan_kernel<<<1, 1024, 0, stream>>>(deg, rowptr);
    scatter_kernel<<<(N_EDGES + 255) / 256, 256, 0, stream>>>(edge_index, edge_attr, rowptr,
                                                              cursor, csr_src, eattr_h, N_EDGES);
    prep_w1e<<<N_LAYERS, 128, 0, stream>>>(msg_w1, w1epk);
    w2u_all<<<N_LAYERS * 129, 128, 0, stream>>>(msg_w2, msg_b2, upd_w, W2u_all, b2u_all);
    // h = x @ node_proj_w + b
    gemm_nodes<IN_CH, false><<<N_NODES / 16, 128, 0, stream>>>(x, node_proj_w, node_proj_b, h);

    for (int l = 0; l < N_LAYERS; l++) {
        const float* mw1 = msg_w1 + (size_t)l * (HID + EDGE_DIM) * HID;
        // nodepart = h @ msg_w1[:128] + msg_b1  (fp16, gathered per edge)
        gemm_nodes<HID, true><<<N_NODES / 16, 128, 0, stream>>>(h, mw1, msg_b1 + l * HID, npart_h);
        // r[n] = sum_{e->n} relu(nodepart[src] + edge_attr @ msg_w1[128:144])
        edge_aggr3<<<N_NODES / EA_NPB, 256, 0, stream>>>(npart_h, w1epk + (size_t)l * 8 * 64 * 2,
                                                         eattr_h, rowptr, csr_src, r);
        // h = relu(LN(relu(h@Wu_top + r@W2u + ub + deg*b2u))) + h
        update_nodes<<<N_NODES / 16, 128, 0, stream>>>(h, r, deg,
                                                       upd_w + (size_t)l * 2 * HID * HID,
                                                       W2u_all + (size_t)l * HID * HID,
                                                       upd_b + l * HID, b2u_all + l * HID,
                                                       ln_g + l * HID, ln_b + l * HID);
    }

    pool_readout<<<N_GRAPHS, 128, 0, stream>>>(h, batch, ffn_w1, ffn_b1, ffn_w2, ffn_b2, out);
}

// Round 5
// 615.520 us; speedup vs baseline: 1.3655x; 1.1139x over previous
//
#include <hip/hip_runtime.h>
#include <hip/hip_fp16.h>
#include <math.h>

#define N_NODES 20000
#define N_EDGES 640000
#define IN_CH 64
#define EDGE_DIM 16
#define HID 128
#define N_LAYERS 3
#define N_GRAPHS 128

typedef _Float16 h2 __attribute__((ext_vector_type(2)));

__device__ inline float fdot2f(h2 a, h2 b, float c) {
#if __has_builtin(__builtin_amdgcn_fdot2)
    return __builtin_amdgcn_fdot2(a, b, c, false);
#else
    float d;
    asm("v_dot2_f32_f16 %0, %1, %2, %3" : "=v"(d) : "v"(a), "v"(b), "v"(c));
    return d;
#endif
}

// ---------------- CSR build ----------------

__global__ void hist_kernel(const int* __restrict__ dst, int* __restrict__ deg, int n) {
    int i = blockIdx.x * blockDim.x + threadIdx.x;
    if (i < n) atomicAdd(&deg[dst[i]], 1);
}

__global__ __launch_bounds__(1024) void scan_kernel(const int* __restrict__ deg,
                                                    int* __restrict__ rowptr) {
    __shared__ int buf[1024];
    const int t = threadIdx.x;
    constexpr int PER = 20;           // 1024*20 >= 20000
    const int base = t * PER;
    int loc[PER];
    int s = 0;
    #pragma unroll
    for (int i = 0; i < PER; i++) {
        int v = (base + i < N_NODES) ? deg[base + i] : 0;
        loc[i] = s; s += v;
    }
    buf[t] = s;
    __syncthreads();
    for (int off = 1; off < 1024; off <<= 1) {
        int x = (t >= off) ? buf[t - off] : 0;
        __syncthreads();
        buf[t] += x;
        __syncthreads();
    }
    const int excl = (t == 0) ? 0 : buf[t - 1];
    #pragma unroll
    for (int i = 0; i < PER; i++)
        if (base + i < N_NODES) rowptr[base + i] = excl + loc[i];
    if (t == 1023) rowptr[N_NODES] = buf[1023];
}

// scatter: assign CSR slot, write src index AND fp16 edge_attr directly into slot order
__global__ __launch_bounds__(256) void scatter_kernel(const int* __restrict__ ei,
                                                      const float* __restrict__ ea,
                                                      const int* __restrict__ rowptr,
                                                      int* __restrict__ cursor,
                                                      int* __restrict__ csr_src,
                                                      __half* __restrict__ eattr, int n) {
    int e = blockIdx.x * blockDim.x + threadIdx.x;
    if (e < n) {
        int d = ei[N_EDGES + e];
        int pos = atomicAdd(&cursor[d], 1);
        int slot = rowptr[d] + pos;
        csr_src[slot] = ei[e];
        const float4* s4 = (const float4*)(ea + (size_t)e * EDGE_DIM);
        const float4 a = s4[0], b = s4[1], c = s4[2], dd = s4[3];
        union { uint4 u; __half2 h[4]; } p0, p1;
        p0.h[0] = __floats2half2_rn(a.x, a.y);  p0.h[1] = __floats2half2_rn(a.z, a.w);
        p0.h[2] = __floats2half2_rn(b.x, b.y);  p0.h[3] = __floats2half2_rn(b.z, b.w);
        p1.h[0] = __floats2half2_rn(c.x, c.y);  p1.h[1] = __floats2half2_rn(c.z, c.w);
        p1.h[2] = __floats2half2_rn(dd.x, dd.y); p1.h[3] = __floats2half2_rn(dd.z, dd.w);
        uint4* o = (uint4*)(eattr + (size_t)slot * EDGE_DIM);
        o[0] = p0.u; o[1] = p1.u;
    }
}

// pack W1e (edge part of msg_w1) into half2 pairs: pk[l][j][c>>1][c&1] = (W[2j][c], W[2j+1][c])
__global__ __launch_bounds__(128) void prep_w1e(const float* __restrict__ msg_w1,
                                                __half2* __restrict__ pk) {
    const int l = blockIdx.x, c = threadIdx.x;
    const float* W1e = msg_w1 + (size_t)l * (HID + EDGE_DIM) * HID + HID * HID;
    #pragma unroll
    for (int j = 0; j < 8; j++) {
        __half2 v = __floats2half2_rn(W1e[(2 * j) * HID + c], W1e[(2 * j + 1) * HID + c]);
        pk[((l * 8 + j) * 64 + (c >> 1)) * 2 + (c & 1)] = v;
    }
}

// ---------------- node GEMM: out[N,128] = in[N,KIN] @ W[KIN,128] + bias ----------------

template<int KIN, bool HALF_OUT>
__global__ __launch_bounds__(128) void gemm_nodes(const float* __restrict__ in,
                                                  const float* __restrict__ W,
                                                  const float* __restrict__ bias,
                                                  void* __restrict__ outp) {
    constexpr int NPB = 16;
    __shared__ __align__(16) float a[NPB * KIN];
    const int t = threadIdx.x;
    const int node0 = blockIdx.x * NPB;
    const float* src = in + (size_t)node0 * KIN;
    #pragma unroll
    for (int i = t * 4; i < NPB * KIN; i += 512)
        *(float4*)(a + i) = *(const float4*)(src + i);
    __syncthreads();
    float acc[NPB];
    const float bv = bias[t];
    #pragma unroll
    for (int n = 0; n < NPB; n++) acc[n] = bv;
    for (int k = 0; k < KIN; k += 4) {
        const float w0 = W[(k + 0) * HID + t];
        const float w1 = W[(k + 1) * HID + t];
        const float w2 = W[(k + 2) * HID + t];
        const float w3 = W[(k + 3) * HID + t];
        #pragma unroll
        for (int n = 0; n < NPB; n++) {
            const float4 av = *(const float4*)(a + n * KIN + k);
            acc[n] += av.x * w0 + av.y * w1 + av.z * w2 + av.w * w3;
        }
    }
    if (HALF_OUT) {
        __half* o = (__half*)outp + (size_t)node0 * HID + t;
        #pragma unroll
        for (int n = 0; n < NPB; n++) o[n * HID] = __float2half(acc[n]);
    } else {
        float* o = (float*)outp + (size_t)node0 * HID + t;
        #pragma unroll
        for (int n = 0; n < NPB; n++) o[n * HID] = acc[n];
    }
}

// ---------------- combined W2u = msg_w2 @ upd_w_bottom, all layers ----------------

__global__ __launch_bounds__(128) void w2u_all(const float* __restrict__ msg_w2,
                                               const float* __restrict__ msg_b2,
                                               const float* __restrict__ upd_w,
                                               float* __restrict__ W2u,
                                               float* __restrict__ b2u) {
    __shared__ float row[HID];
    const int t = threadIdx.x;
    const int l = blockIdx.x / 129, d = blockIdx.x % 129;
    const float* w2 = msg_w2 + (size_t)l * HID * HID;
    const float* wu_bot = upd_w + (size_t)l * 2 * HID * HID + HID * HID;
    const float* src = (d < HID) ? (w2 + d * HID) : (msg_b2 + l * HID);
    row[t] = src[t];
    __syncthreads();
    float acc = 0.f;
    for (int k = 0; k < HID; k++) acc += row[k] * wu_bot[k * HID + t];
    if (d < HID) W2u[(size_t)l * HID * HID + d * HID + t] = acc;
    else b2u[l * HID + t] = acc;
}

// -------- edge aggregate: r[n] = sum_{e: dst=n} relu(npart[src] + ea@W1e) --------
// One wave per node: no barriers, no LDS. 4-edge groups, gathers hoisted for MLP.

__global__ __launch_bounds__(256) void edge_aggr4(const __half* __restrict__ npart,
                                                  const __half2* __restrict__ w1epk,
                                                  const __half* __restrict__ eattr,
                                                  const int* __restrict__ rowptr,
                                                  const int* __restrict__ csr_src,
                                                  float* __restrict__ r) {
    const int t = threadIdx.x;
    const int w = t >> 6, l = t & 63;
    const int node = blockIdx.x * 4 + w;
    h2 wk0[8], wk1[8];
    const uint2* wp = (const uint2*)w1epk;
    #pragma unroll
    for (int j = 0; j < 8; j++) {
        union { uint u; h2 h; } q0, q1;
        const uint2 q = wp[j * 64 + l];
        q0.u = q.x; q1.u = q.y;
        wk0[j] = q0.h; wk1[j] = q1.h;
    }
    const int beg = rowptr[node], end = rowptr[node + 1];
    float acc0 = 0.f, acc1 = 0.f;
    int i = beg;
    for (; i + 4 <= end; i += 4) {
        int s[4];
        #pragma unroll
        for (int j = 0; j < 4; j++) s[j] = csr_src[i + j];
        h2 hv[4];
        #pragma unroll
        for (int j = 0; j < 4; j++)
            hv[j] = *(const h2*)(npart + (size_t)s[j] * HID + 2 * l);
        #pragma unroll
        for (int j = 0; j < 4; j++) {
            union { uint4 u; h2 h[4]; } ea, eb;
            const uint4* ep = (const uint4*)(eattr + (size_t)(i + j) * EDGE_DIM);
            ea.u = ep[0]; eb.u = ep[1];
            float z0 = (float)hv[j].x, z1 = (float)hv[j].y;
            #pragma unroll
            for (int k = 0; k < 4; k++) {
                z0 = fdot2f(ea.h[k], wk0[k], z0);
                z1 = fdot2f(ea.h[k], wk1[k], z1);
            }
            #pragma unroll
            for (int k = 0; k < 4; k++) {
                z0 = fdot2f(eb.h[k], wk0[4 + k], z0);
                z1 = fdot2f(eb.h[k], wk1[4 + k], z1);
            }
            acc0 += fmaxf(z0, 0.f);
            acc1 += fmaxf(z1, 0.f);
        }
    }
    for (; i < end; i++) {
        const int s0 = csr_src[i];
        const h2 hv0 = *(const h2*)(npart + (size_t)s0 * HID + 2 * l);
        union { uint4 u; h2 h[4]; } ea, eb;
        const uint4* ep = (const uint4*)(eattr + (size_t)i * EDGE_DIM);
        ea.u = ep[0]; eb.u = ep[1];
        float z0 = (float)hv0.x, z1 = (float)hv0.y;
        #pragma unroll
        for (int k = 0; k < 4; k++) {
            z0 = fdot2f(ea.h[k], wk0[k], z0);
            z1 = fdot2f(ea.h[k], wk1[k], z1);
        }
        #pragma unroll
        for (int k = 0; k < 4; k++) {
            z0 = fdot2f(eb.h[k], wk0[4 + k], z0);
            z1 = fdot2f(eb.h[k], wk1[4 + k], z1);
        }
        acc0 += fmaxf(z0, 0.f);
        acc1 += fmaxf(z1, 0.f);
    }
    *(float2*)(r + (size_t)node * HID + 2 * l) = make_float2(acc0, acc1);
}

// ------- fused update + LayerNorm + relu + residual (in-place on h), optionally emitting
// ------- npart = new_h @ nw1 + nb1 (fp16) for the NEXT layer's message MLP -------

template<bool EMIT>
__global__ __launch_bounds__(128) void update_nodes(float* __restrict__ h,
                                                    const float* __restrict__ r,
                                                    const int* __restrict__ deg,
                                                    const float* __restrict__ Wt,
                                                    const float* __restrict__ W2u,
                                                    const float* __restrict__ ub,
                                                    const float* __restrict__ b2u,
                                                    const float* __restrict__ lng,
                                                    const float* __restrict__ lnb,
                                                    const float* __restrict__ nw1,
                                                    const float* __restrict__ nb1,
                                                    __half* __restrict__ npart) {
    constexpr int NPB = 16;
    __shared__ __align__(16) float sh[NPB * HID];
    __shared__ __align__(16) float sr[NPB * HID];
    __shared__ float smu[NPB], srs[NPB];
    const int t = threadIdx.x;
    const int node0 = blockIdx.x * NPB;
    #pragma unroll
    for (int i = t * 4; i < NPB * HID; i += 512) {
        *(float4*)(sh + i) = *(const float4*)(h + (size_t)node0 * HID + i);
        *(float4*)(sr + i) = *(const float4*)(r + (size_t)node0 * HID + i);
    }
    __syncthreads();
    float acc[NPB];
    const float ubv = ub[t], b2uv = b2u[t];
    #pragma unroll
    for (int n = 0; n < NPB; n++) acc[n] = ubv + (float)deg[node0 + n] * b2uv;
    for (int k = 0; k < HID; k += 4) {
        const float wt0 = Wt[(k + 0) * HID + t], w20 = W2u[(k + 0) * HID + t];
        const float wt1 = Wt[(k + 1) * HID + t], w21 = W2u[(k + 1) * HID + t];
        const float wt2 = Wt[(k + 2) * HID + t], w22 = W2u[(k + 2) * HID + t];
        const float wt3 = Wt[(k + 3) * HID + t], w23 = W2u[(k + 3) * HID + t];
        #pragma unroll
        for (int n = 0; n < NPB; n++) {
            const float4 hv = *(const float4*)(sh + n * HID + k);
            const float4 rv = *(const float4*)(sr + n * HID + k);
            acc[n] += hv.x * wt0 + hv.y * wt1 + hv.z * wt2 + hv.w * wt3;
            acc[n] += rv.x * w20 + rv.y * w21 + rv.z * w22 + rv.w * w23;
        }
    }
    #pragma unroll
    for (int n = 0; n < NPB; n++) acc[n] = fmaxf(acc[n], 0.f);
    __syncthreads();
    #pragma unroll
    for (int n = 0; n < NPB; n++) sr[n * HID + t] = acc[n];
    __syncthreads();
    {
        const int n = t >> 3, lane = t & 7;
        float s = 0.f, ss = 0.f;
        #pragma unroll
        for (int i = 0; i < 16; i++) {
            float v = sr[n * HID + lane + i * 8];
            s += v; ss += v * v;
        }
        s += __shfl_xor(s, 1); ss += __shfl_xor(ss, 1);
        s += __shfl_xor(s, 2); ss += __shfl_xor(ss, 2);
        s += __shfl_xor(s, 4); ss += __shfl_xor(ss, 4);
        if (lane == 0) {
            float mu = s * (1.f / HID);
            float var = ss * (1.f / HID) - mu * mu;
            smu[n] = mu;
            srs[n] = rsqrtf(var + 1e-5f);
        }
    }
    __syncthreads();
    const float g = lng[t], b = lnb[t];
    #pragma unroll
    for (int n = 0; n < NPB; n++) {
        float v = (acc[n] - smu[n]) * srs[n] * g + b;
        v = fmaxf(v, 0.f) + sh[n * HID + t];     // new h (thread t reads only column t)
        acc[n] = v;
        h[(size_t)(node0 + n) * HID + t] = v;
    }
    if (EMIT) {
        __syncthreads();                          // all done reading old sh columns
        #pragma unroll
        for (int n = 0; n < NPB; n++) sh[n * HID + t] = acc[n];   // sh := new h
        __syncthreads();
        float acc2[NPB];
        const float nbv = nb1[t];
        #pragma unroll
        for (int n = 0; n < NPB; n++) acc2[n] = nbv;
        for (int k = 0; k < HID; k += 4) {
            const float w0 = nw1[(k + 0) * HID + t];
            const float w1 = nw1[(k + 1) * HID + t];
            const float w2 = nw1[(k + 2) * HID + t];
            const float w3 = nw1[(k + 3) * HID + t];
            #pragma unroll
            for (int n = 0; n < NPB; n++) {
                const float4 hv = *(const float4*)(sh + n * HID + k);
                acc2[n] += hv.x * w0 + hv.y * w1 + hv.z * w2 + hv.w * w3;
            }
        }
        __half* o = npart + (size_t)node0 * HID + t;
        #pragma unroll
        for (int n = 0; n < NPB; n++) o[n * HID] = __float2half(acc2[n]);
    }
}

// ---------------- fused pooling + readout (batch is sorted -> segment scan, no atomics) ----------------

__global__ __launch_bounds__(128) void pool_readout(const float* __restrict__ h,
                                                    const int* __restrict__ batch,
                                                    const float* __restrict__ w1,
                                                    const float* __restrict__ b1,
                                                    const float* __restrict__ w2,
                                                    const float* __restrict__ b2,
                                                    float* __restrict__ out) {
    __shared__ int sbe[2];
    __shared__ float g[2 * HID];
    __shared__ float red[2];
    const int t = threadIdx.x, gi = blockIdx.x;
    if (t < 2) {
        const int target = gi + t;
        int lo = 0, hi = N_NODES;
        while (lo < hi) { int m = (lo + hi) >> 1; if (batch[m] < target) lo = m + 1; else hi = m; }
        sbe[t] = lo;
    }
    __syncthreads();
    const int beg = sbe[0], end = sbe[1];
    float sum = 0.f, mx = -INFINITY;
    int n = beg;
    for (; n + 4 <= end; n += 4) {
        const float v0 = h[(size_t)(n + 0) * HID + t];
        const float v1 = h[(size_t)(n + 1) * HID + t];
        const float v2 = h[(size_t)(n + 2) * HID + t];
        const float v3 = h[(size_t)(n + 3) * HID + t];
        sum += v0 + v1 + v2 + v3;
        mx = fmaxf(mx, fmaxf(fmaxf(v0, v1), fmaxf(v2, v3)));
    }
    for (; n < end; n++) { const float v = h[(size_t)n * HID + t]; sum += v; mx = fmaxf(mx, v); }
    const float c = fmaxf((float)(end - beg), 1.f);
    g[t] = sum / c;
    g[HID + t] = mx;
    __syncthreads();
    float acc = b1[t];
    for (int k = 0; k < 2 * HID; k++) acc += g[k] * w1[k * HID + t];
    float s = fmaxf(acc, 0.f) * w2[t];
    s += __shfl_down(s, 32); s += __shfl_down(s, 16); s += __shfl_down(s, 8);
    s += __shfl_down(s, 4);  s += __shfl_down(s, 2);  s += __shfl_down(s, 1);
    if ((t & 63) == 0) red[t >> 6] = s;
    __syncthreads();
    if (t == 0) out[gi] = red[0] + red[1] + b2[0];
}

// ---------------- launch ----------------

extern "C" void kernel_launch(void* const* d_in, const int* in_sizes, int n_in,
                              void* d_out, int out_size, void* d_ws, size_t ws_size,
                              hipStream_t stream) {
    const float* x           = (const float*)d_in[0];
    const int*   edge_index  = (const int*)  d_in[1];
    const float* edge_attr   = (const float*)d_in[2];
    const int*   batch       = (const int*)  d_in[3];
    const float* node_proj_w = (const float*)d_in[4];
    const float* node_proj_b = (const float*)d_in[5];
    const float* msg_w1      = (const float*)d_in[6];
    const float* msg_b1      = (const float*)d_in[7];
    const float* msg_w2      = (const float*)d_in[8];
    const float* msg_b2      = (const float*)d_in[9];
    const float* upd_w       = (const float*)d_in[10];
    const float* upd_b       = (const float*)d_in[11];
    const float* ln_g        = (const float*)d_in[12];
    const float* ln_b        = (const float*)d_in[13];
    const float* ffn_w1      = (const float*)d_in[14];
    const float* ffn_b1      = (const float*)d_in[15];
    const float* ffn_w2      = (const float*)d_in[16];
    const float* ffn_b2      = (const float*)d_in[17];
    float* out = (float*)d_out;

    char* ws = (char*)d_ws;
    size_t off = 0;
    auto alloc = [&](size_t b) -> char* {
        char* p = ws + off;
        off = (off + b + 255) & ~(size_t)255;
        return p;
    };
    float*    h        = (float*)alloc((size_t)N_NODES * HID * 4);
    __half*   npart_h  = (__half*)alloc((size_t)N_NODES * HID * 2);
    float*    r        = (float*)alloc((size_t)N_NODES * HID * 4);
    float*    W2u_all  = (float*)alloc((size_t)N_LAYERS * HID * HID * 4);
    float*    b2u_all  = (float*)alloc((size_t)N_LAYERS * HID * 4);
    __half2*  w1epk    = (__half2*)alloc((size_t)N_LAYERS * 8 * 64 * 2 * 4);
    int*      rowptr   = (int*)alloc((N_NODES + 1) * 4);
    int*      deg      = (int*)alloc((size_t)N_NODES * 4 * 2);  // deg + cursor contiguous
    int*      cursor   = deg + N_NODES;
    int*      csr_src  = (int*)alloc((size_t)N_EDGES * 4);
    __half*   eattr_h  = (__half*)alloc((size_t)N_EDGES * EDGE_DIM * 2);
    (void)in_sizes; (void)n_in; (void)out_size; (void)ws_size;

    // CSR build (per call; ws is re-poisoned each launch)
    hipMemsetAsync(deg, 0, (size_t)N_NODES * 4 * 2, stream);
    hist_kernel<<<(N_EDGES + 255) / 256, 256, 0, stream>>>(edge_index + N_EDGES, deg, N_EDGES);
    scan_kernel<<<1, 1024, 0, stream>>>(deg, rowptr);
    scatter_kernel<<<(N_EDGES + 255) / 256, 256, 0, stream>>>(edge_index, edge_attr, rowptr,
                                                              cursor, csr_src, eattr_h, N_EDGES);
    prep_w1e<<<N_LAYERS, 128, 0, stream>>>(msg_w1, w1epk);
    w2u_all<<<N_LAYERS * 129, 128, 0, stream>>>(msg_w2, msg_b2, upd_w, W2u_all, b2u_all);
    // h = x @ node_proj_w + b
    gemm_nodes<IN_CH, false><<<N_NODES / 16, 128, 0, stream>>>(x, node_proj_w, node_proj_b, h);
    // layer-0 npart
    gemm_nodes<HID, true><<<N_NODES / 16, 128, 0, stream>>>(h, msg_w1, msg_b1, npart_h);

    for (int l = 0; l < N_LAYERS; l++) {
        // r[n] = sum_{e->n} relu(npart[src] + edge_attr @ msg_w1[128:144])
        edge_aggr4<<<N_NODES / 4, 256, 0, stream>>>(npart_h, w1epk + (size_t)l * 8 * 64 * 2,
                                                    eattr_h, rowptr, csr_src, r);
        // h = relu(LN(relu(h@Wu_top + r@W2u + ub + deg*b2u))) + h ; emit npart for next layer
        const bool emit = (l + 1 < N_LAYERS);
        const float* nw1 = msg_w1 + (size_t)(l + 1) * (HID + EDGE_DIM) * HID;
        const float* nb1 = msg_b1 + (size_t)(l + 1) * HID;
        if (emit)
            update_nodes<true><<<N_NODES / 16, 128, 0, stream>>>(
                h, r, deg, upd_w + (size_t)l * 2 * HID * HID,
                W2u_all + (size_t)l * HID * HID, upd_b + l * HID, b2u_all + l * HID,
                ln_g + l * HID, ln_b + l * HID, nw1, nb1, npart_h);
        else
            update_nodes<false><<<N_NODES / 16, 128, 0, stream>>>(
                h, r, deg, upd_w + (size_t)l * 2 * HID * HID,
                W2u_all + (size_t)l * HID * HID, upd_b + l * HID, b2u_all + l * HID,
                ln_g + l * HID, ln_b + l * HID, nullptr, nullptr, nullptr);
    }

    pool_readout<<<N_GRAPHS, 128, 0, stream>>>(h, batch, ffn_w1, ffn_b1, ffn_w2, ffn_b2, out);
}